// Round 7
// baseline (981.228 us; speedup 1.0000x reference)
//
#include <hip/hip_runtime.h>
#include <hip/hip_bf16.h>

#define B_N 16384
#define D_N 512
#define K_N 2048

typedef __attribute__((ext_vector_type(8))) short bf16x8;
typedef __attribute__((ext_vector_type(4))) float f32x4;
typedef __attribute__((ext_vector_type(4))) unsigned short u16x4;
typedef unsigned short u16;

__device__ __forceinline__ float bf2f(short s) {
  return __builtin_bit_cast(float, ((unsigned)(u16)s) << 16);
}
__device__ __forceinline__ u16 f2bf(float x) {
  return __builtin_bit_cast(u16, __float2bfloat16(x));
}
__device__ __forceinline__ unsigned fbits(float x) {
  return __builtin_bit_cast(unsigned, x);
}
__device__ __forceinline__ float wred_sum(float v) {
#pragma unroll
  for (int o = 32; o; o >>= 1) v += __shfl_down(v, o, 64);
  return v;
}

__device__ __forceinline__ void gld16(const u16* g, const u16* l) {
  __builtin_amdgcn_global_load_lds((const __attribute__((address_space(1))) void*)g,
                                   (__attribute__((address_space(3))) void*)l, 16, 0, 0);
}

// ---------------- row l2norm + bf16 convert (normalized + raw) ----------------
__global__ __launch_bounds__(256) void k_rownorm(const float* __restrict__ z1,
                                                 const float* __restrict__ z2,
                                                 u16* __restrict__ zn1, u16* __restrict__ zn2,
                                                 u16* __restrict__ zb1, u16* __restrict__ zb2) {
  int wid = threadIdx.x >> 6, lane = threadIdx.x & 63;
  int row = blockIdx.x * 4 + wid;
  const float* z; u16 *zn, *zb; int r;
  if (row < B_N) { z = z1; zn = zn1; zb = zb1; r = row; }
  else { z = z2; zn = zn2; zb = zb2; r = row - B_N; }
  const float4* zr = (const float4*)(z + (size_t)r * D_N);
  float4 va = zr[lane], vb = zr[lane + 64];
  float ss = va.x*va.x + va.y*va.y + va.z*va.z + va.w*va.w
           + vb.x*vb.x + vb.y*vb.y + vb.z*vb.z + vb.w*vb.w;
#pragma unroll
  for (int o = 32; o; o >>= 1) ss += __shfl_xor(ss, o, 64);
  float inv = 1.0f / fmaxf(sqrtf(ss), 1e-12f);
  u16x4 pa = {f2bf(va.x), f2bf(va.y), f2bf(va.z), f2bf(va.w)};
  u16x4 pb = {f2bf(vb.x), f2bf(vb.y), f2bf(vb.z), f2bf(vb.w)};
  u16x4 na = {f2bf(va.x*inv), f2bf(va.y*inv), f2bf(va.z*inv), f2bf(va.w*inv)};
  u16x4 nb = {f2bf(vb.x*inv), f2bf(vb.y*inv), f2bf(vb.z*inv), f2bf(vb.w*inv)};
  ((u16x4*)(zb + (size_t)r * D_N))[lane] = pa;
  ((u16x4*)(zb + (size_t)r * D_N))[lane + 64] = pb;
  ((u16x4*)(zn + (size_t)r * D_N))[lane] = na;
  ((u16x4*)(zn + (size_t)r * D_N))[lane + 64] = nb;
}

// ---------------- W -> bf16 ----------------
__global__ __launch_bounds__(256) void k_convW(const float* __restrict__ W,
                                               u16* __restrict__ Wb) {
  size_t base = ((size_t)blockIdx.x * 256 + threadIdx.x) * 8;
#pragma unroll
  for (int j = 0; j < 8; j++) Wb[base + j] = f2bf(W[base + j]);
}

// ---------------- per-column sum / sumsq (bf16 input) ----------------
__global__ __launch_bounds__(512) void k_colstats(const u16* __restrict__ zb1,
                                                  const u16* __restrict__ zb2,
                                                  float* __restrict__ csum,
                                                  float* __restrict__ csumsq) {
  int zi = blockIdx.z;
  const u16* z = zi ? zb2 : zb1;
  __shared__ float s1[512], s2[512];
  int t = threadIdx.y * 64 + threadIdx.x;
  s1[t] = 0.f; s2[t] = 0.f;
  __syncthreads();
  int c0 = threadIdx.x * 8;
  float a[8], a2[8];
#pragma unroll
  for (int e = 0; e < 8; e++) { a[e] = 0.f; a2[e] = 0.f; }
  for (int u = 0; u < 16; u++) {
    int r = blockIdx.y * 128 + threadIdx.y + 8 * u;
    bf16x8 v = *(const bf16x8*)&z[(size_t)r * D_N + c0];
#pragma unroll
    for (int e = 0; e < 8; e++) { float x = bf2f(v[e]); a[e] += x; a2[e] += x * x; }
  }
#pragma unroll
  for (int e = 0; e < 8; e++) {
    atomicAdd(&s1[c0 + e], a[e]);
    atomicAdd(&s2[c0 + e], a2[e]);
  }
  __syncthreads();
  atomicAdd(&csum[zi * D_N + t], s1[t]);
  atomicAdd(&csumsq[zi * D_N + t], s2[t]);
}

// ---------------- variance hinge loss ----------------
__global__ __launch_bounds__(256) void k_vloss(const float* __restrict__ csum,
                                               const float* __restrict__ csumsq,
                                               float* __restrict__ scal) {
  int idx = blockIdx.x * 256 + threadIdx.x;  // < 1024
  float s = csum[idx], sq = csumsq[idx];
  float mean = s * (1.0f / (float)B_N);
  float var = (sq - (float)B_N * mean * mean) * (1.0f / (float)(B_N - 1));
  float term = fmaxf(0.f, 0.2f - sqrtf(var + 1e-8f));
  term = wred_sum(term);
  __shared__ float sw[4];
  if ((threadIdx.x & 63) == 0) sw[threadIdx.x >> 6] = term;
  __syncthreads();
  if (threadIdx.x == 0) atomicAdd(&scal[0], sw[0] + sw[1] + sw[2] + sw[3]);
}

// ---------------- gram (bf16 input, upper-triangle tiles, split-K 16) ----------------
__global__ __launch_bounds__(256) void k_gram(const u16* __restrict__ zb1,
                                              const u16* __restrict__ zb2,
                                              float* __restrict__ Gpart) {
  int zi = blockIdx.z >> 4, chunk = blockIdx.z & 15;
  const u16* z = zi ? zb2 : zb1;
  int ti = 0, xx = blockIdx.x;
  while (xx >= 8 - ti) { xx -= 8 - ti; ti++; }
  int tj = ti + xx;
  int i0 = ti * 64, j0 = tj * 64;
  __shared__ u16 lA[64][32], lB[64][32];
  int t = threadIdx.x, wid = t >> 6, lane = t & 63;
  int br = t & 31, fg = t >> 5;
  f32x4 acc[4];
#pragma unroll
  for (int q = 0; q < 4; q++) acc[q] = (f32x4){0.f, 0.f, 0.f, 0.f};
  for (int bb = 0; bb < 1024; bb += 32) {
    size_t rb = ((size_t)chunk * 1024 + bb + br) * D_N;
    bf16x8 va = *(const bf16x8*)&z[rb + i0 + fg * 8];
    bf16x8 vb = *(const bf16x8*)&z[rb + j0 + fg * 8];
#pragma unroll
    for (int e = 0; e < 8; e++) {
      lA[fg * 8 + e][br] = (u16)va[e];
      lB[fg * 8 + e][br] = (u16)vb[e];
    }
    __syncthreads();
    int m = lane & 15, q = lane >> 4;
    bf16x8 a = *(const bf16x8*)&lA[16 * wid + m][8 * q];
#pragma unroll
    for (int tt = 0; tt < 4; tt++) {
      bf16x8 b = *(const bf16x8*)&lB[16 * tt + m][8 * q];
      acc[tt] = __builtin_amdgcn_mfma_f32_16x16x32_bf16(a, b, acc[tt], 0, 0, 0);
    }
    __syncthreads();
  }
  float* gp = Gpart + (((size_t)zi * 16 + chunk) * 36 + blockIdx.x) * 4096;
  int n = lane & 15, q = lane >> 4;
#pragma unroll
  for (int tt = 0; tt < 4; tt++)
#pragma unroll
    for (int r = 0; r < 4; r++)
      gp[(16 * wid + q * 4 + r) * 64 + 16 * tt + n] = acc[tt][r];
}

// ---------------- covariance off-diag reduce (triangle, weighted) ----------------
__global__ __launch_bounds__(256) void k_covreduce(const float* __restrict__ Gpart,
                                                   const float* __restrict__ csum,
                                                   float* __restrict__ scal) {
  int zi = blockIdx.y;
  int tile = blockIdx.x >> 4, part = blockIdx.x & 15;
  int ti = 0, xx = tile;
  while (xx >= 8 - ti) { xx -= 8 - ti; ti++; }
  int tj = ti + xx;
  int idx = part * 256 + threadIdx.x;
  int li = idx >> 6, lj = idx & 63;
  int i = ti * 64 + li, j = tj * 64 + lj;
  float g = 0.f;
#pragma unroll
  for (int c = 0; c < 16; c++)
    g += Gpart[(((size_t)zi * 16 + c) * 36 + tile) * 4096 + idx];
  float mi = csum[zi * D_N + i] * (1.0f / (float)B_N);
  float mj = csum[zi * D_N + j] * (1.0f / (float)B_N);
  float C = (g - (float)B_N * mi * mj) * (1.0f / (float)(B_N - 1));
  float wgt = (ti == tj) ? ((li == lj) ? 0.f : 1.f) : 2.f;
  float v = wgt * C * C;
  v = wred_sum(v);
  __shared__ float sw[4];
  if ((threadIdx.x & 63) == 0) sw[threadIdx.x >> 6] = v;
  __syncthreads();
  if (threadIdx.x == 0) atomicAdd(&scal[1], sw[0] + sw[1] + sw[2] + sw[3]);
}

// ---------------- logits = zn @ W^T, 128x128 tile, global_load_lds; fused rs0 ----------------
__global__ __launch_bounds__(256) void k_logits(const u16* __restrict__ zn1,
                                                const u16* __restrict__ zn2,
                                                const u16* __restrict__ Wb,
                                                u16* __restrict__ L1, u16* __restrict__ L2,
                                                float* __restrict__ rowsum) {
  int zi = blockIdx.z;
  const u16* A = zi ? zn2 : zn1;
  u16* Lout = zi ? L2 : L1;
  int b0 = blockIdx.x * 128, k0 = blockIdx.y * 128;
  __shared__ u16 lA[128 * 32], lB[128 * 32];
  int t = threadIdx.x, lane = t & 63, wid = t >> 6;
  int wm = wid >> 1, wn = wid & 1;
  f32x4 acc[4][4];
#pragma unroll
  for (int i = 0; i < 4; i++)
#pragma unroll
    for (int j = 0; j < 4; j++) acc[i][j] = (f32x4){0.f, 0.f, 0.f, 0.f};
  int row0 = t >> 2, seg0 = (t & 3) * 8;
  int ldsoff = (t & 192) * 16;  // wave-uniform byte offset
  for (int d0 = 0; d0 < D_N; d0 += 32) {
    gld16(A + (size_t)(b0 + row0) * D_N + d0 + seg0, (const u16*)((const char*)lA + ldsoff));
    gld16(A + (size_t)(b0 + 64 + row0) * D_N + d0 + seg0, (const u16*)((const char*)lA + 4096 + ldsoff));
    gld16(Wb + (size_t)(k0 + row0) * D_N + d0 + seg0, (const u16*)((const char*)lB + ldsoff));
    gld16(Wb + (size_t)(k0 + 64 + row0) * D_N + d0 + seg0, (const u16*)((const char*)lB + 4096 + ldsoff));
    __syncthreads();
    bf16x8 af[4], bfr[4];
#pragma unroll
    for (int i = 0; i < 4; i++)
      af[i] = *(const bf16x8*)&lA[(wm * 64 + i * 16 + (lane & 15)) * 32 + (lane >> 4) * 8];
#pragma unroll
    for (int j = 0; j < 4; j++)
      bfr[j] = *(const bf16x8*)&lB[(wn * 64 + j * 16 + (lane & 15)) * 32 + (lane >> 4) * 8];
#pragma unroll
    for (int i = 0; i < 4; i++)
#pragma unroll
      for (int j = 0; j < 4; j++)
        acc[i][j] = __builtin_amdgcn_mfma_f32_16x16x32_bf16(af[i], bfr[j], acc[i][j], 0, 0, 0);
    __syncthreads();
  }
  int cq = lane >> 4, cn = lane & 15;
  float rpart[4] = {0.f, 0.f, 0.f, 0.f};
#pragma unroll
  for (int i = 0; i < 4; i++)
#pragma unroll
    for (int j = 0; j < 4; j++)
#pragma unroll
      for (int r = 0; r < 4; r++) {
        u16 h = f2bf(acc[i][j][r]);
        int gb = b0 + wm * 64 + i * 16 + cq * 4 + r;
        int gk = k0 + wn * 64 + j * 16 + cn;
        Lout[(size_t)gb * K_N + gk] = h;
        rpart[j] += __expf(20.0f * bf2f((short)h));
      }
  float* red = (float*)lA;
  if (t < 128) red[t] = 0.f;
  __syncthreads();
#pragma unroll
  for (int j = 0; j < 4; j++) atomicAdd(&red[wn * 64 + j * 16 + cn], rpart[j]);
  __syncthreads();
  if (t < 128) atomicAdd(&rowsum[(size_t)zi * 3 * K_N + k0 + t], red[t]);
}

// ---------------- fused sinkhorn half-iteration pair ----------------
// c_it[b] = sum_k E[b,k]*r_it[k]  (in-wave), then rs_{it+1}[k] += E[b,k]/(B*c_it[b])
// pm permuted: phys(k) = (k&7)*256 + (k>>3) -> per-lane atomics lane-consecutive.
__global__ __launch_bounds__(256) void k_sink(const u16* __restrict__ L1,
                                              const u16* __restrict__ L2,
                                              float* __restrict__ rowsum, int it) {
  int zi = blockIdx.y;
  const u16* L = zi ? L2 : L1;
  const float* rs_in = rowsum + ((size_t)zi * 3 + it) * K_N;
  float* rs_out = rowsum + ((size_t)zi * 3 + it + 1) * K_N;
  __shared__ float pm[K_N];
  int t = threadIdx.x, lane = t & 63, wid = t >> 6;
  for (int k = t; k < K_N; k += 256) pm[k] = 0.f;
  float rv[32];
#pragma unroll
  for (int jj = 0; jj < 4; jj++) {
    const float4* p = (const float4*)&rs_in[jj * 512 + lane * 8];
    float4 x = p[0], y = p[1];
    rv[jj*8+0] = 1.0f / ((float)K_N * x.x); rv[jj*8+1] = 1.0f / ((float)K_N * x.y);
    rv[jj*8+2] = 1.0f / ((float)K_N * x.z); rv[jj*8+3] = 1.0f / ((float)K_N * x.w);
    rv[jj*8+4] = 1.0f / ((float)K_N * y.x); rv[jj*8+5] = 1.0f / ((float)K_N * y.y);
    rv[jj*8+6] = 1.0f / ((float)K_N * y.z); rv[jj*8+7] = 1.0f / ((float)K_N * y.w);
  }
  __syncthreads();
  float racc[32];
#pragma unroll
  for (int q = 0; q < 32; q++) racc[q] = 0.f;
  int w = blockIdx.x * 4 + wid;  // 0..2047
  for (int rr = 0; rr < 8; rr++) {
    int b = w * 8 + rr;
    float ex[32];
    float c = 0.f;
#pragma unroll
    for (int jj = 0; jj < 4; jj++) {
      bf16x8 v = *(const bf16x8*)&L[(size_t)b * K_N + jj * 512 + lane * 8];
#pragma unroll
      for (int e = 0; e < 8; e++) {
        float E = __expf(20.0f * bf2f(v[e]));
        ex[jj * 8 + e] = E;
        c += E * rv[jj * 8 + e];
      }
    }
#pragma unroll
    for (int o = 32; o; o >>= 1) c += __shfl_xor(c, o, 64);
    float cb = 1.0f / ((float)B_N * c);
#pragma unroll
    for (int q = 0; q < 32; q++) racc[q] += ex[q] * cb;
  }
#pragma unroll
  for (int q = 0; q < 32; q++)
    atomicAdd(&pm[(q & 7) * 256 + (q >> 3) * 64 + lane], racc[q]);
  __syncthreads();
  for (int k = t; k < K_N; k += 256)
    atomicAdd(&rs_out[k], pm[(k & 7) * 256 + (k >> 3)]);
}

// ---------------- final fused pass: CE + diagnostics ----------------
// 8 rows/wave in 4 pairs; r tables + probs accumulator all in registers;
// NO per-row LDS traffic (LDS atomics serialize per lane); one global-atomic
// merge per wave at the end. Packed-u32 argmax. LDS usage: zero.
__global__ __launch_bounds__(256, 2) void k_final(const u16* __restrict__ L1,
                                                  const u16* __restrict__ L2,
                                                  const float* __restrict__ rowsum,
                                                  float* __restrict__ probsum,
                                                  int* __restrict__ counts,
                                                  float* __restrict__ scal) {
  const float* rs1 = rowsum + 2 * K_N;
  const float* rs2 = rowsum + 5 * K_N;
  int t = threadIdx.x, lane = t & 63, wid = t >> 6;
  float rv1[32], rv2[32];
#pragma unroll
  for (int jj = 0; jj < 4; jj++) {
    const float4* p1 = (const float4*)&rs1[jj * 512 + lane * 8];
    const float4* p2 = (const float4*)&rs2[jj * 512 + lane * 8];
    float4 x1 = p1[0], y1 = p1[1], x2 = p2[0], y2 = p2[1];
    rv1[jj*8+0] = 1.0f/((float)K_N*x1.x); rv1[jj*8+1] = 1.0f/((float)K_N*x1.y);
    rv1[jj*8+2] = 1.0f/((float)K_N*x1.z); rv1[jj*8+3] = 1.0f/((float)K_N*x1.w);
    rv1[jj*8+4] = 1.0f/((float)K_N*y1.x); rv1[jj*8+5] = 1.0f/((float)K_N*y1.y);
    rv1[jj*8+6] = 1.0f/((float)K_N*y1.z); rv1[jj*8+7] = 1.0f/((float)K_N*y1.w);
    rv2[jj*8+0] = 1.0f/((float)K_N*x2.x); rv2[jj*8+1] = 1.0f/((float)K_N*x2.y);
    rv2[jj*8+2] = 1.0f/((float)K_N*x2.z); rv2[jj*8+3] = 1.0f/((float)K_N*x2.w);
    rv2[jj*8+4] = 1.0f/((float)K_N*y2.x); rv2[jj*8+5] = 1.0f/((float)K_N*y2.y);
    rv2[jj*8+6] = 1.0f/((float)K_N*y2.z); rv2[jj*8+7] = 1.0f/((float)K_N*y2.w);
  }
  float pacc[32];
#pragma unroll
  for (int q = 0; q < 32; q++) pacc[q] = 0.f;
  float ce_acc = 0.f; int acc_cnt = 0;
  int w = blockIdx.x * 4 + wid;  // 0..2047
  for (int pp = 0; pp < 4; pp++) {
    int ba = w * 8 + pp * 2;  // pair rows: ba, ba+1
    bf16x8 va1[4], va2[4], vb1[4], vb2[4];
#pragma unroll
    for (int jj = 0; jj < 4; jj++) {
      va1[jj] = *(const bf16x8*)&L1[(size_t)ba * K_N + jj * 512 + lane * 8];
      va2[jj] = *(const bf16x8*)&L2[(size_t)ba * K_N + jj * 512 + lane * 8];
      vb1[jj] = *(const bf16x8*)&L1[(size_t)(ba + 1) * K_N + jj * 512 + lane * 8];
      vb2[jj] = *(const bf16x8*)&L2[(size_t)(ba + 1) * K_N + jj * 512 + lane * 8];
    }
    float sE1a=0,sE2a=0,d12a=0,d21a=0,Z1a=0,Z2a=0;
    float sE1b=0,sE2b=0,d12b=0,d21b=0,Z1b=0,Z2b=0;
    unsigned um1a=0,um2a=0,ua1a=0,ua2a=0;
    unsigned um1b=0,um2b=0,ua1b=0,ua2b=0;
#pragma unroll
    for (int jj = 0; jj < 4; jj++)
#pragma unroll
      for (int e = 0; e < 8; e++) {
        int q = jj * 8 + e;
        unsigned ik = 2047u - (unsigned)(jj * 512 + lane * 8 + e);
        float x1 = bf2f(va1[jj][e]), x2 = bf2f(va2[jj][e]);
        float t1 = __expf(10.0f * x1), t2 = __expf(10.0f * x2);
        float e1 = t1 * t1 * rv1[q], e2 = t2 * t2 * rv2[q];
        sE1a += e1; sE2a += e2; d12a += e1 * x2; d21a += e2 * x1; Z1a += t1; Z2a += t2;
        um1a = max(um1a, (fbits(t1) & 0xFFFFF800u) | ik);
        um2a = max(um2a, (fbits(t2) & 0xFFFFF800u) | ik);
        ua1a = max(ua1a, (fbits(e1) & 0xFFFFF800u) | ik);
        ua2a = max(ua2a, (fbits(e2) & 0xFFFFF800u) | ik);
        x1 = bf2f(vb1[jj][e]); x2 = bf2f(vb2[jj][e]);
        t1 = __expf(10.0f * x1); t2 = __expf(10.0f * x2);
        e1 = t1 * t1 * rv1[q]; e2 = t2 * t2 * rv2[q];
        sE1b += e1; sE2b += e2; d12b += e1 * x2; d21b += e2 * x1; Z1b += t1; Z2b += t2;
        um1b = max(um1b, (fbits(t1) & 0xFFFFF800u) | ik);
        um2b = max(um2b, (fbits(t2) & 0xFFFFF800u) | ik);
        ua1b = max(ua1b, (fbits(e1) & 0xFFFFF800u) | ik);
        ua2b = max(ua2b, (fbits(e2) & 0xFFFFF800u) | ik);
      }
#pragma unroll
    for (int o = 32; o; o >>= 1) {
      sE1a += __shfl_xor(sE1a, o, 64); sE2a += __shfl_xor(sE2a, o, 64);
      d12a += __shfl_xor(d12a, o, 64); d21a += __shfl_xor(d21a, o, 64);
      Z1a += __shfl_xor(Z1a, o, 64);   Z2a += __shfl_xor(Z2a, o, 64);
      sE1b += __shfl_xor(sE1b, o, 64); sE2b += __shfl_xor(sE2b, o, 64);
      d12b += __shfl_xor(d12b, o, 64); d21b += __shfl_xor(d21b, o, 64);
      Z1b += __shfl_xor(Z1b, o, 64);   Z2b += __shfl_xor(Z2b, o, 64);
      um1a = max(um1a, (unsigned)__shfl_xor((int)um1a, o, 64));
      um2a = max(um2a, (unsigned)__shfl_xor((int)um2a, o, 64));
      ua1a = max(ua1a, (unsigned)__shfl_xor((int)ua1a, o, 64));
      ua2a = max(ua2a, (unsigned)__shfl_xor((int)ua2a, o, 64));
      um1b = max(um1b, (unsigned)__shfl_xor((int)um1b, o, 64));
      um2b = max(um2b, (unsigned)__shfl_xor((int)um2b, o, 64));
      ua1b = max(ua1b, (unsigned)__shfl_xor((int)ua1b, o, 64));
      ua2b = max(ua2b, (unsigned)__shfl_xor((int)ua2b, o, 64));
    }
    // row a epilogue (cs2 final colsum == sE; argmax(20x+log r) == argmax e)
    {
      int m1i = 2047 - (int)(um1a & 2047u), m2i = 2047 - (int)(um2a & 2047u);
      int a1i = 2047 - (int)(ua1a & 2047u), a2i = 2047 - (int)(ua2a & 2047u);
      float invc1 = 1.0f / sE1a, invc2 = 1.0f / sE2a;
      ce_acc += (10.0f * d12a) * invc1 - __logf(Z2a) + (10.0f * d21a) * invc2 - __logf(Z1a);
      acc_cnt += (m1i == a2i) + (m2i == a1i);
      if (lane == 0) { atomicAdd(&counts[m1i], 1); atomicAdd(&counts[m2i], 1); }
      float iZ1 = 1.0f / Z1a, iZ2 = 1.0f / Z2a;
#pragma unroll
      for (int jj = 0; jj < 4; jj++)
#pragma unroll
        for (int e = 0; e < 8; e++)
          pacc[jj * 8 + e] += __expf(10.0f * bf2f(va1[jj][e])) * iZ1
                            + __expf(10.0f * bf2f(va2[jj][e])) * iZ2;
    }
    // row b epilogue
    {
      int m1i = 2047 - (int)(um1b & 2047u), m2i = 2047 - (int)(um2b & 2047u);
      int a1i = 2047 - (int)(ua1b & 2047u), a2i = 2047 - (int)(ua2b & 2047u);
      float invc1 = 1.0f / sE1b, invc2 = 1.0f / sE2b;
      ce_acc += (10.0f * d12b) * invc1 - __logf(Z2b) + (10.0f * d21b) * invc2 - __logf(Z1b);
      acc_cnt += (m1i == a2i) + (m2i == a1i);
      if (lane == 0) { atomicAdd(&counts[m1i], 1); atomicAdd(&counts[m2i], 1); }
      float iZ1 = 1.0f / Z1b, iZ2 = 1.0f / Z2b;
#pragma unroll
      for (int jj = 0; jj < 4; jj++)
#pragma unroll
        for (int e = 0; e < 8; e++)
          pacc[jj * 8 + e] += __expf(10.0f * bf2f(vb1[jj][e])) * iZ1
                            + __expf(10.0f * bf2f(vb2[jj][e])) * iZ2;
    }
  }
  if (lane == 0) {
    atomicAdd(&scal[2], ce_acc);
    atomicAdd(&scal[3], (float)acc_cnt);
  }
  // single merge per wave: 32 coalesced-ish fire-and-forget global atomics
#pragma unroll
  for (int q = 0; q < 32; q++)
    atomicAdd(&probsum[(q >> 3) * 512 + lane * 8 + (q & 7)], pacc[q]);
}

// ---------------- combine: all 7 outputs ----------------
__global__ __launch_bounds__(256) void k_combine(const float* __restrict__ scal,
                                                 const float* __restrict__ probsum,
                                                 const int* __restrict__ counts,
                                                 float* __restrict__ out) {
  int t = threadIdx.x;
  float ec = 0.f, ep = 0.f;
  for (int k = t; k < K_N; k += 256) {
    float p = (float)counts[k] * (1.0f / (2.0f * (float)B_N));
    ec += -p * __logf(p + 1e-7f);
    float q = probsum[k] * (1.0f / (2.0f * (float)B_N));
    ep += -q * __logf(q + 1e-7f);
  }
  ec = wred_sum(ec);
  ep = wred_sum(ep);
  __shared__ float se[4], sp[4];
  if ((t & 63) == 0) { se[t >> 6] = ec; sp[t >> 6] = ep; }
  __syncthreads();
  if (t == 0) {
    float tec = se[0] + se[1] + se[2] + se[3];
    float tep = sp[0] + sp[1] + sp[2] + sp[3];
    float ce = -0.5f * scal[2] * (1.0f / (float)B_N);
    float lvar = scal[0] * (1.0f / (float)D_N);
    float lcov = scal[1] * (1.0f / (float)D_N);
    float acc = scal[3] * (1.0f / (2.0f * (float)B_N));
    out[0] = 15.0f * ce + lvar + lcov;
    out[1] = ce;
    out[2] = lvar;
    out[3] = lcov;
    out[4] = __expf(tec);
    out[5] = __expf(tep);
    out[6] = acc;
  }
}

extern "C" void kernel_launch(void* const* d_in, const int* in_sizes, int n_in,
                              void* d_out, int out_size, void* d_ws, size_t ws_size,
                              hipStream_t stream) {
  (void)in_sizes; (void)n_in; (void)out_size; (void)ws_size;
  const float* z1 = (const float*)d_in[0];
  const float* z2 = (const float*)d_in[1];
  const float* W = (const float*)d_in[2];

  char* w = (char*)d_ws;
  size_t off = 0;
  auto take = [&](size_t b) -> void* {
    void* p = w + off;
    off = (off + b + 255) & ~(size_t)255;
    return p;
  };
  float* rowsum = (float*)take(2 * 3 * K_N * 4);
  float* csum = (float*)take(2 * D_N * 4);
  float* csumsq = (float*)take(2 * D_N * 4);
  float* probsum = (float*)take(K_N * 4);
  int* counts = (int*)take(K_N * 4);
  float* scal = (float*)take(64);
  size_t zero_bytes = off;
  u16* zn1 = (u16*)take((size_t)B_N * D_N * 2);
  u16* zn2 = (u16*)take((size_t)B_N * D_N * 2);
  u16* Wb = (u16*)take((size_t)K_N * D_N * 2);
  u16* L1 = (u16*)take((size_t)B_N * K_N * 2);
  u16* L2 = (u16*)take((size_t)B_N * K_N * 2);
  float* Gpart = (float*)take((size_t)2 * 16 * 36 * 4096 * 4);
  // raw-bf16 z aliases the (not yet live) L1 buffer; gram/colstats finish before k_logits
  u16* zb1 = L1;
  u16* zb2 = L1 + (size_t)B_N * D_N;

  hipMemsetAsync(d_ws, 0, zero_bytes, stream);

  k_rownorm<<<8192, 256, 0, stream>>>(z1, z2, zn1, zn2, zb1, zb2);
  k_convW<<<512, 256, 0, stream>>>(W, Wb);
  k_colstats<<<dim3(1, 128, 2), dim3(64, 8), 0, stream>>>(zb1, zb2, csum, csumsq);
  k_vloss<<<4, 256, 0, stream>>>(csum, csumsq, scal);
  k_gram<<<dim3(36, 1, 32), 256, 0, stream>>>(zb1, zb2, Gpart);
  k_covreduce<<<dim3(36 * 16, 2), 256, 0, stream>>>(Gpart, csum, scal);
  k_logits<<<dim3(128, 16, 2), 256, 0, stream>>>(zn1, zn2, Wb, L1, L2, rowsum);
  k_sink<<<dim3(512, 2), 256, 0, stream>>>(L1, L2, rowsum, 0);
  k_sink<<<dim3(512, 2), 256, 0, stream>>>(L1, L2, rowsum, 1);
  k_final<<<512, 256, 0, stream>>>(L1, L2, rowsum, probsum, counts, scal);
  k_combine<<<1, 256, 0, stream>>>(scal, probsum, counts, (float*)d_out);
}

// Round 8
// 547.556 us; speedup vs baseline: 1.7920x; 1.7920x over previous
//
#include <hip/hip_runtime.h>
#include <hip/hip_bf16.h>

#define B_N 16384
#define D_N 512
#define K_N 2048

typedef __attribute__((ext_vector_type(8))) short bf16x8;
typedef __attribute__((ext_vector_type(4))) float f32x4;
typedef __attribute__((ext_vector_type(4))) unsigned short u16x4;
typedef unsigned short u16;

__device__ __forceinline__ float bf2f(short s) {
  return __builtin_bit_cast(float, ((unsigned)(u16)s) << 16);
}
__device__ __forceinline__ u16 f2bf(float x) {
  return __builtin_bit_cast(u16, __float2bfloat16(x));
}
__device__ __forceinline__ unsigned fbits(float x) {
  return __builtin_bit_cast(unsigned, x);
}
__device__ __forceinline__ float wred_sum(float v) {
#pragma unroll
  for (int o = 32; o; o >>= 1) v += __shfl_down(v, o, 64);
  return v;
}

__device__ __forceinline__ void gld16(const u16* g, const u16* l) {
  __builtin_amdgcn_global_load_lds((const __attribute__((address_space(1))) void*)g,
                                   (__attribute__((address_space(3))) void*)l, 16, 0, 0);
}

// ---------------- row l2norm + bf16 convert (normalized + raw) ----------------
__global__ __launch_bounds__(256) void k_rownorm(const float* __restrict__ z1,
                                                 const float* __restrict__ z2,
                                                 u16* __restrict__ zn1, u16* __restrict__ zn2,
                                                 u16* __restrict__ zb1, u16* __restrict__ zb2) {
  int wid = threadIdx.x >> 6, lane = threadIdx.x & 63;
  int row = blockIdx.x * 4 + wid;
  const float* z; u16 *zn, *zb; int r;
  if (row < B_N) { z = z1; zn = zn1; zb = zb1; r = row; }
  else { z = z2; zn = zn2; zb = zb2; r = row - B_N; }
  const float4* zr = (const float4*)(z + (size_t)r * D_N);
  float4 va = zr[lane], vb = zr[lane + 64];
  float ss = va.x*va.x + va.y*va.y + va.z*va.z + va.w*va.w
           + vb.x*vb.x + vb.y*vb.y + vb.z*vb.z + vb.w*vb.w;
#pragma unroll
  for (int o = 32; o; o >>= 1) ss += __shfl_xor(ss, o, 64);
  float inv = 1.0f / fmaxf(sqrtf(ss), 1e-12f);
  u16x4 pa = {f2bf(va.x), f2bf(va.y), f2bf(va.z), f2bf(va.w)};
  u16x4 pb = {f2bf(vb.x), f2bf(vb.y), f2bf(vb.z), f2bf(vb.w)};
  u16x4 na = {f2bf(va.x*inv), f2bf(va.y*inv), f2bf(va.z*inv), f2bf(va.w*inv)};
  u16x4 nb = {f2bf(vb.x*inv), f2bf(vb.y*inv), f2bf(vb.z*inv), f2bf(vb.w*inv)};
  ((u16x4*)(zb + (size_t)r * D_N))[lane] = pa;
  ((u16x4*)(zb + (size_t)r * D_N))[lane + 64] = pb;
  ((u16x4*)(zn + (size_t)r * D_N))[lane] = na;
  ((u16x4*)(zn + (size_t)r * D_N))[lane + 64] = nb;
}

// ---------------- W -> bf16 ----------------
__global__ __launch_bounds__(256) void k_convW(const float* __restrict__ W,
                                               u16* __restrict__ Wb) {
  size_t base = ((size_t)blockIdx.x * 256 + threadIdx.x) * 8;
#pragma unroll
  for (int j = 0; j < 8; j++) Wb[base + j] = f2bf(W[base + j]);
}

// ---------------- per-column sum / sumsq (bf16 input) ----------------
__global__ __launch_bounds__(512) void k_colstats(const u16* __restrict__ zb1,
                                                  const u16* __restrict__ zb2,
                                                  float* __restrict__ csum,
                                                  float* __restrict__ csumsq) {
  int zi = blockIdx.z;
  const u16* z = zi ? zb2 : zb1;
  __shared__ float s1[512], s2[512];
  int t = threadIdx.y * 64 + threadIdx.x;
  s1[t] = 0.f; s2[t] = 0.f;
  __syncthreads();
  int c0 = threadIdx.x * 8;
  float a[8], a2[8];
#pragma unroll
  for (int e = 0; e < 8; e++) { a[e] = 0.f; a2[e] = 0.f; }
  for (int u = 0; u < 16; u++) {
    int r = blockIdx.y * 128 + threadIdx.y + 8 * u;
    bf16x8 v = *(const bf16x8*)&z[(size_t)r * D_N + c0];
#pragma unroll
    for (int e = 0; e < 8; e++) { float x = bf2f(v[e]); a[e] += x; a2[e] += x * x; }
  }
#pragma unroll
  for (int e = 0; e < 8; e++) {
    atomicAdd(&s1[c0 + e], a[e]);
    atomicAdd(&s2[c0 + e], a2[e]);
  }
  __syncthreads();
  atomicAdd(&csum[zi * D_N + t], s1[t]);
  atomicAdd(&csumsq[zi * D_N + t], s2[t]);
}

// ---------------- variance hinge loss ----------------
__global__ __launch_bounds__(256) void k_vloss(const float* __restrict__ csum,
                                               const float* __restrict__ csumsq,
                                               float* __restrict__ scal) {
  int idx = blockIdx.x * 256 + threadIdx.x;  // < 1024
  float s = csum[idx], sq = csumsq[idx];
  float mean = s * (1.0f / (float)B_N);
  float var = (sq - (float)B_N * mean * mean) * (1.0f / (float)(B_N - 1));
  float term = fmaxf(0.f, 0.2f - sqrtf(var + 1e-8f));
  term = wred_sum(term);
  __shared__ float sw[4];
  if ((threadIdx.x & 63) == 0) sw[threadIdx.x >> 6] = term;
  __syncthreads();
  if (threadIdx.x == 0) atomicAdd(&scal[0], sw[0] + sw[1] + sw[2] + sw[3]);
}

// ---------------- gram (bf16 input, upper-triangle tiles, split-K 16) ----------------
__global__ __launch_bounds__(256) void k_gram(const u16* __restrict__ zb1,
                                              const u16* __restrict__ zb2,
                                              float* __restrict__ Gpart) {
  int zi = blockIdx.z >> 4, chunk = blockIdx.z & 15;
  const u16* z = zi ? zb2 : zb1;
  int ti = 0, xx = blockIdx.x;
  while (xx >= 8 - ti) { xx -= 8 - ti; ti++; }
  int tj = ti + xx;
  int i0 = ti * 64, j0 = tj * 64;
  __shared__ u16 lA[64][32], lB[64][32];
  int t = threadIdx.x, wid = t >> 6, lane = t & 63;
  int br = t & 31, fg = t >> 5;
  f32x4 acc[4];
#pragma unroll
  for (int q = 0; q < 4; q++) acc[q] = (f32x4){0.f, 0.f, 0.f, 0.f};
  for (int bb = 0; bb < 1024; bb += 32) {
    size_t rb = ((size_t)chunk * 1024 + bb + br) * D_N;
    bf16x8 va = *(const bf16x8*)&z[rb + i0 + fg * 8];
    bf16x8 vb = *(const bf16x8*)&z[rb + j0 + fg * 8];
#pragma unroll
    for (int e = 0; e < 8; e++) {
      lA[fg * 8 + e][br] = (u16)va[e];
      lB[fg * 8 + e][br] = (u16)vb[e];
    }
    __syncthreads();
    int m = lane & 15, q = lane >> 4;
    bf16x8 a = *(const bf16x8*)&lA[16 * wid + m][8 * q];
#pragma unroll
    for (int tt = 0; tt < 4; tt++) {
      bf16x8 b = *(const bf16x8*)&lB[16 * tt + m][8 * q];
      acc[tt] = __builtin_amdgcn_mfma_f32_16x16x32_bf16(a, b, acc[tt], 0, 0, 0);
    }
    __syncthreads();
  }
  float* gp = Gpart + (((size_t)zi * 16 + chunk) * 36 + blockIdx.x) * 4096;
  int n = lane & 15, q = lane >> 4;
#pragma unroll
  for (int tt = 0; tt < 4; tt++)
#pragma unroll
    for (int r = 0; r < 4; r++)
      gp[(16 * wid + q * 4 + r) * 64 + 16 * tt + n] = acc[tt][r];
}

// ---------------- covariance off-diag reduce (triangle, weighted) ----------------
__global__ __launch_bounds__(256) void k_covreduce(const float* __restrict__ Gpart,
                                                   const float* __restrict__ csum,
                                                   float* __restrict__ scal) {
  int zi = blockIdx.y;
  int tile = blockIdx.x >> 4, part = blockIdx.x & 15;
  int ti = 0, xx = tile;
  while (xx >= 8 - ti) { xx -= 8 - ti; ti++; }
  int tj = ti + xx;
  int idx = part * 256 + threadIdx.x;
  int li = idx >> 6, lj = idx & 63;
  int i = ti * 64 + li, j = tj * 64 + lj;
  float g = 0.f;
#pragma unroll
  for (int c = 0; c < 16; c++)
    g += Gpart[(((size_t)zi * 16 + c) * 36 + tile) * 4096 + idx];
  float mi = csum[zi * D_N + i] * (1.0f / (float)B_N);
  float mj = csum[zi * D_N + j] * (1.0f / (float)B_N);
  float C = (g - (float)B_N * mi * mj) * (1.0f / (float)(B_N - 1));
  float wgt = (ti == tj) ? ((li == lj) ? 0.f : 1.f) : 2.f;
  float v = wgt * C * C;
  v = wred_sum(v);
  __shared__ float sw[4];
  if ((threadIdx.x & 63) == 0) sw[threadIdx.x >> 6] = v;
  __syncthreads();
  if (threadIdx.x == 0) atomicAdd(&scal[1], sw[0] + sw[1] + sw[2] + sw[3]);
}

// ---------------- logits = zn @ W^T, 128x128 tile, global_load_lds; fused rs0 ----------------
__global__ __launch_bounds__(256) void k_logits(const u16* __restrict__ zn1,
                                                const u16* __restrict__ zn2,
                                                const u16* __restrict__ Wb,
                                                u16* __restrict__ L1, u16* __restrict__ L2,
                                                float* __restrict__ rowsum) {
  int zi = blockIdx.z;
  const u16* A = zi ? zn2 : zn1;
  u16* Lout = zi ? L2 : L1;
  int b0 = blockIdx.x * 128, k0 = blockIdx.y * 128;
  __shared__ u16 lA[128 * 32], lB[128 * 32];
  int t = threadIdx.x, lane = t & 63, wid = t >> 6;
  int wm = wid >> 1, wn = wid & 1;
  f32x4 acc[4][4];
#pragma unroll
  for (int i = 0; i < 4; i++)
#pragma unroll
    for (int j = 0; j < 4; j++) acc[i][j] = (f32x4){0.f, 0.f, 0.f, 0.f};
  int row0 = t >> 2, seg0 = (t & 3) * 8;
  int ldsoff = (t & 192) * 16;  // wave-uniform byte offset
  for (int d0 = 0; d0 < D_N; d0 += 32) {
    gld16(A + (size_t)(b0 + row0) * D_N + d0 + seg0, (const u16*)((const char*)lA + ldsoff));
    gld16(A + (size_t)(b0 + 64 + row0) * D_N + d0 + seg0, (const u16*)((const char*)lA + 4096 + ldsoff));
    gld16(Wb + (size_t)(k0 + row0) * D_N + d0 + seg0, (const u16*)((const char*)lB + ldsoff));
    gld16(Wb + (size_t)(k0 + 64 + row0) * D_N + d0 + seg0, (const u16*)((const char*)lB + 4096 + ldsoff));
    __syncthreads();
    bf16x8 af[4], bfr[4];
#pragma unroll
    for (int i = 0; i < 4; i++)
      af[i] = *(const bf16x8*)&lA[(wm * 64 + i * 16 + (lane & 15)) * 32 + (lane >> 4) * 8];
#pragma unroll
    for (int j = 0; j < 4; j++)
      bfr[j] = *(const bf16x8*)&lB[(wn * 64 + j * 16 + (lane & 15)) * 32 + (lane >> 4) * 8];
#pragma unroll
    for (int i = 0; i < 4; i++)
#pragma unroll
      for (int j = 0; j < 4; j++)
        acc[i][j] = __builtin_amdgcn_mfma_f32_16x16x32_bf16(af[i], bfr[j], acc[i][j], 0, 0, 0);
    __syncthreads();
  }
  int cq = lane >> 4, cn = lane & 15;
  float rpart[4] = {0.f, 0.f, 0.f, 0.f};
#pragma unroll
  for (int i = 0; i < 4; i++)
#pragma unroll
    for (int j = 0; j < 4; j++)
#pragma unroll
      for (int r = 0; r < 4; r++) {
        u16 h = f2bf(acc[i][j][r]);
        int gb = b0 + wm * 64 + i * 16 + cq * 4 + r;
        int gk = k0 + wn * 64 + j * 16 + cn;
        Lout[(size_t)gb * K_N + gk] = h;
        rpart[j] += __expf(20.0f * bf2f((short)h));
      }
  float* red = (float*)lA;
  if (t < 128) red[t] = 0.f;
  __syncthreads();
#pragma unroll
  for (int j = 0; j < 4; j++) atomicAdd(&red[wn * 64 + j * 16 + cn], rpart[j]);
  __syncthreads();
  if (t < 128) atomicAdd(&rowsum[(size_t)zi * 3 * K_N + k0 + t], red[t]);
}

// ---------------- fused sinkhorn half-iteration pair ----------------
// c_it[b] = sum_k E[b,k]*r_it[k]  (in-wave), then rs_{it+1}[k] += E[b,k]/(B*c_it[b])
// pm permuted: phys(k) = (k&7)*256 + (k>>3) -> per-lane atomics lane-consecutive.
__global__ __launch_bounds__(256) void k_sink(const u16* __restrict__ L1,
                                              const u16* __restrict__ L2,
                                              float* __restrict__ rowsum, int it) {
  int zi = blockIdx.y;
  const u16* L = zi ? L2 : L1;
  const float* rs_in = rowsum + ((size_t)zi * 3 + it) * K_N;
  float* rs_out = rowsum + ((size_t)zi * 3 + it + 1) * K_N;
  __shared__ float pm[K_N];
  int t = threadIdx.x, lane = t & 63, wid = t >> 6;
  for (int k = t; k < K_N; k += 256) pm[k] = 0.f;
  float rv[32];
#pragma unroll
  for (int jj = 0; jj < 4; jj++) {
    const float4* p = (const float4*)&rs_in[jj * 512 + lane * 8];
    float4 x = p[0], y = p[1];
    rv[jj*8+0] = 1.0f / ((float)K_N * x.x); rv[jj*8+1] = 1.0f / ((float)K_N * x.y);
    rv[jj*8+2] = 1.0f / ((float)K_N * x.z); rv[jj*8+3] = 1.0f / ((float)K_N * x.w);
    rv[jj*8+4] = 1.0f / ((float)K_N * y.x); rv[jj*8+5] = 1.0f / ((float)K_N * y.y);
    rv[jj*8+6] = 1.0f / ((float)K_N * y.z); rv[jj*8+7] = 1.0f / ((float)K_N * y.w);
  }
  __syncthreads();
  float racc[32];
#pragma unroll
  for (int q = 0; q < 32; q++) racc[q] = 0.f;
  int w = blockIdx.x * 4 + wid;  // 0..2047
  for (int rr = 0; rr < 8; rr++) {
    int b = w * 8 + rr;
    float ex[32];
    float c = 0.f;
#pragma unroll
    for (int jj = 0; jj < 4; jj++) {
      bf16x8 v = *(const bf16x8*)&L[(size_t)b * K_N + jj * 512 + lane * 8];
#pragma unroll
      for (int e = 0; e < 8; e++) {
        float E = __expf(20.0f * bf2f(v[e]));
        ex[jj * 8 + e] = E;
        c += E * rv[jj * 8 + e];
      }
    }
#pragma unroll
    for (int o = 32; o; o >>= 1) c += __shfl_xor(c, o, 64);
    float cb = 1.0f / ((float)B_N * c);
#pragma unroll
    for (int q = 0; q < 32; q++) racc[q] += ex[q] * cb;
  }
#pragma unroll
  for (int q = 0; q < 32; q++)
    atomicAdd(&pm[(q & 7) * 256 + (q >> 3) * 64 + lane], racc[q]);
  __syncthreads();
  for (int k = t; k < K_N; k += 256)
    atomicAdd(&rs_out[k], pm[(k & 7) * 256 + (k >> 3)]);
}

// ---------------- final fused pass: CE + diagnostics ----------------
// 16 rows/wave in 8 ILP-pairs; r tables + probs accumulator in registers;
// hot loop touches NO LDS; one permuted-LDS merge per wave at the end
// (conflict-free), then one global atomic per k per block. Packed-u32 argmax.
__global__ __launch_bounds__(256, 2) void k_final(const u16* __restrict__ L1,
                                                  const u16* __restrict__ L2,
                                                  const float* __restrict__ rowsum,
                                                  float* __restrict__ probsum,
                                                  int* __restrict__ counts,
                                                  float* __restrict__ scal) {
  __shared__ float pmerge[K_N];
  const float* rs1 = rowsum + 2 * K_N;
  const float* rs2 = rowsum + 5 * K_N;
  int t = threadIdx.x, lane = t & 63, wid = t >> 6;
  for (int k = t; k < K_N; k += 256) pmerge[k] = 0.f;
  float rv1[32], rv2[32];
#pragma unroll
  for (int jj = 0; jj < 4; jj++) {
    const float4* p1 = (const float4*)&rs1[jj * 512 + lane * 8];
    const float4* p2 = (const float4*)&rs2[jj * 512 + lane * 8];
    float4 x1 = p1[0], y1 = p1[1], x2 = p2[0], y2 = p2[1];
    rv1[jj*8+0] = 1.0f/((float)K_N*x1.x); rv1[jj*8+1] = 1.0f/((float)K_N*x1.y);
    rv1[jj*8+2] = 1.0f/((float)K_N*x1.z); rv1[jj*8+3] = 1.0f/((float)K_N*x1.w);
    rv1[jj*8+4] = 1.0f/((float)K_N*y1.x); rv1[jj*8+5] = 1.0f/((float)K_N*y1.y);
    rv1[jj*8+6] = 1.0f/((float)K_N*y1.z); rv1[jj*8+7] = 1.0f/((float)K_N*y1.w);
    rv2[jj*8+0] = 1.0f/((float)K_N*x2.x); rv2[jj*8+1] = 1.0f/((float)K_N*x2.y);
    rv2[jj*8+2] = 1.0f/((float)K_N*x2.z); rv2[jj*8+3] = 1.0f/((float)K_N*x2.w);
    rv2[jj*8+4] = 1.0f/((float)K_N*y2.x); rv2[jj*8+5] = 1.0f/((float)K_N*y2.y);
    rv2[jj*8+6] = 1.0f/((float)K_N*y2.z); rv2[jj*8+7] = 1.0f/((float)K_N*y2.w);
  }
  __syncthreads();
  float pacc[32];
#pragma unroll
  for (int q = 0; q < 32; q++) pacc[q] = 0.f;
  float ce_acc = 0.f; int acc_cnt = 0;
  int w = blockIdx.x * 4 + wid;  // 0..1023
  for (int pp = 0; pp < 8; pp++) {
    int ba = w * 16 + pp * 2;  // pair rows: ba, ba+1
    bf16x8 va1[4], va2[4], vb1[4], vb2[4];
#pragma unroll
    for (int jj = 0; jj < 4; jj++) {
      va1[jj] = *(const bf16x8*)&L1[(size_t)ba * K_N + jj * 512 + lane * 8];
      va2[jj] = *(const bf16x8*)&L2[(size_t)ba * K_N + jj * 512 + lane * 8];
      vb1[jj] = *(const bf16x8*)&L1[(size_t)(ba + 1) * K_N + jj * 512 + lane * 8];
      vb2[jj] = *(const bf16x8*)&L2[(size_t)(ba + 1) * K_N + jj * 512 + lane * 8];
    }
    float sE1a=0,sE2a=0,d12a=0,d21a=0,Z1a=0,Z2a=0;
    float sE1b=0,sE2b=0,d12b=0,d21b=0,Z1b=0,Z2b=0;
    unsigned um1a=0,um2a=0,ua1a=0,ua2a=0;
    unsigned um1b=0,um2b=0,ua1b=0,ua2b=0;
#pragma unroll
    for (int jj = 0; jj < 4; jj++)
#pragma unroll
      for (int e = 0; e < 8; e++) {
        int q = jj * 8 + e;
        unsigned ik = 2047u - (unsigned)(jj * 512 + lane * 8 + e);
        float x1 = bf2f(va1[jj][e]), x2 = bf2f(va2[jj][e]);
        float t1 = __expf(10.0f * x1), t2 = __expf(10.0f * x2);
        float e1 = t1 * t1 * rv1[q], e2 = t2 * t2 * rv2[q];
        sE1a += e1; sE2a += e2; d12a += e1 * x2; d21a += e2 * x1; Z1a += t1; Z2a += t2;
        um1a = max(um1a, (fbits(t1) & 0xFFFFF800u) | ik);
        um2a = max(um2a, (fbits(t2) & 0xFFFFF800u) | ik);
        ua1a = max(ua1a, (fbits(e1) & 0xFFFFF800u) | ik);
        ua2a = max(ua2a, (fbits(e2) & 0xFFFFF800u) | ik);
        x1 = bf2f(vb1[jj][e]); x2 = bf2f(vb2[jj][e]);
        t1 = __expf(10.0f * x1); t2 = __expf(10.0f * x2);
        e1 = t1 * t1 * rv1[q]; e2 = t2 * t2 * rv2[q];
        sE1b += e1; sE2b += e2; d12b += e1 * x2; d21b += e2 * x1; Z1b += t1; Z2b += t2;
        um1b = max(um1b, (fbits(t1) & 0xFFFFF800u) | ik);
        um2b = max(um2b, (fbits(t2) & 0xFFFFF800u) | ik);
        ua1b = max(ua1b, (fbits(e1) & 0xFFFFF800u) | ik);
        ua2b = max(ua2b, (fbits(e2) & 0xFFFFF800u) | ik);
      }
#pragma unroll
    for (int o = 32; o; o >>= 1) {
      sE1a += __shfl_xor(sE1a, o, 64); sE2a += __shfl_xor(sE2a, o, 64);
      d12a += __shfl_xor(d12a, o, 64); d21a += __shfl_xor(d21a, o, 64);
      Z1a += __shfl_xor(Z1a, o, 64);   Z2a += __shfl_xor(Z2a, o, 64);
      sE1b += __shfl_xor(sE1b, o, 64); sE2b += __shfl_xor(sE2b, o, 64);
      d12b += __shfl_xor(d12b, o, 64); d21b += __shfl_xor(d21b, o, 64);
      Z1b += __shfl_xor(Z1b, o, 64);   Z2b += __shfl_xor(Z2b, o, 64);
      um1a = max(um1a, (unsigned)__shfl_xor((int)um1a, o, 64));
      um2a = max(um2a, (unsigned)__shfl_xor((int)um2a, o, 64));
      ua1a = max(ua1a, (unsigned)__shfl_xor((int)ua1a, o, 64));
      ua2a = max(ua2a, (unsigned)__shfl_xor((int)ua2a, o, 64));
      um1b = max(um1b, (unsigned)__shfl_xor((int)um1b, o, 64));
      um2b = max(um2b, (unsigned)__shfl_xor((int)um2b, o, 64));
      ua1b = max(ua1b, (unsigned)__shfl_xor((int)ua1b, o, 64));
      ua2b = max(ua2b, (unsigned)__shfl_xor((int)ua2b, o, 64));
    }
    // row a epilogue (cs2 final colsum == sE; argmax(20x+log r) == argmax e)
    {
      int m1i = 2047 - (int)(um1a & 2047u), m2i = 2047 - (int)(um2a & 2047u);
      int a1i = 2047 - (int)(ua1a & 2047u), a2i = 2047 - (int)(ua2a & 2047u);
      float invc1 = 1.0f / sE1a, invc2 = 1.0f / sE2a;
      ce_acc += (10.0f * d12a) * invc1 - __logf(Z2a) + (10.0f * d21a) * invc2 - __logf(Z1a);
      acc_cnt += (m1i == a2i) + (m2i == a1i);
      if (lane == 0) { atomicAdd(&counts[m1i], 1); atomicAdd(&counts[m2i], 1); }
      float iZ1 = 1.0f / Z1a, iZ2 = 1.0f / Z2a;
#pragma unroll
      for (int jj = 0; jj < 4; jj++)
#pragma unroll
        for (int e = 0; e < 8; e++)
          pacc[jj * 8 + e] += __expf(10.0f * bf2f(va1[jj][e])) * iZ1
                            + __expf(10.0f * bf2f(va2[jj][e])) * iZ2;
    }
    // row b epilogue
    {
      int m1i = 2047 - (int)(um1b & 2047u), m2i = 2047 - (int)(um2b & 2047u);
      int a1i = 2047 - (int)(ua1b & 2047u), a2i = 2047 - (int)(ua2b & 2047u);
      float invc1 = 1.0f / sE1b, invc2 = 1.0f / sE2b;
      ce_acc += (10.0f * d12b) * invc1 - __logf(Z2b) + (10.0f * d21b) * invc2 - __logf(Z1b);
      acc_cnt += (m1i == a2i) + (m2i == a1i);
      if (lane == 0) { atomicAdd(&counts[m1i], 1); atomicAdd(&counts[m2i], 1); }
      float iZ1 = 1.0f / Z1b, iZ2 = 1.0f / Z2b;
#pragma unroll
      for (int jj = 0; jj < 4; jj++)
#pragma unroll
        for (int e = 0; e < 8; e++)
          pacc[jj * 8 + e] += __expf(10.0f * bf2f(vb1[jj][e])) * iZ1
                            + __expf(10.0f * bf2f(vb2[jj][e])) * iZ2;
    }
  }
  if (lane == 0) {
    atomicAdd(&scal[2], ce_acc);
    atomicAdd(&scal[3], (float)acc_cnt);
  }
  // one LDS merge per wave (permuted layout -> lane-consecutive, conflict-free)
#pragma unroll
  for (int q = 0; q < 32; q++)
    atomicAdd(&pmerge[(q & 7) * 256 + (q >> 3) * 64 + lane], pacc[q]);
  __syncthreads();
  // one global atomic per k per block; probsum in permuted slots (order-free sum)
  for (int k = t; k < K_N; k += 256) atomicAdd(&probsum[k], pmerge[k]);
}

// ---------------- combine: all 7 outputs ----------------
__global__ __launch_bounds__(256) void k_combine(const float* __restrict__ scal,
                                                 const float* __restrict__ probsum,
                                                 const int* __restrict__ counts,
                                                 float* __restrict__ out) {
  int t = threadIdx.x;
  float ec = 0.f, ep = 0.f;
  for (int k = t; k < K_N; k += 256) {
    float p = (float)counts[k] * (1.0f / (2.0f * (float)B_N));
    ec += -p * __logf(p + 1e-7f);
    float q = probsum[k] * (1.0f / (2.0f * (float)B_N));
    ep += -q * __logf(q + 1e-7f);
  }
  ec = wred_sum(ec);
  ep = wred_sum(ep);
  __shared__ float se[4], sp[4];
  if ((t & 63) == 0) { se[t >> 6] = ec; sp[t >> 6] = ep; }
  __syncthreads();
  if (t == 0) {
    float tec = se[0] + se[1] + se[2] + se[3];
    float tep = sp[0] + sp[1] + sp[2] + sp[3];
    float ce = -0.5f * scal[2] * (1.0f / (float)B_N);
    float lvar = scal[0] * (1.0f / (float)D_N);
    float lcov = scal[1] * (1.0f / (float)D_N);
    float acc = scal[3] * (1.0f / (2.0f * (float)B_N));
    out[0] = 15.0f * ce + lvar + lcov;
    out[1] = ce;
    out[2] = lvar;
    out[3] = lcov;
    out[4] = __expf(tec);
    out[5] = __expf(tep);
    out[6] = acc;
  }
}

extern "C" void kernel_launch(void* const* d_in, const int* in_sizes, int n_in,
                              void* d_out, int out_size, void* d_ws, size_t ws_size,
                              hipStream_t stream) {
  (void)in_sizes; (void)n_in; (void)out_size; (void)ws_size;
  const float* z1 = (const float*)d_in[0];
  const float* z2 = (const float*)d_in[1];
  const float* W = (const float*)d_in[2];

  char* w = (char*)d_ws;
  size_t off = 0;
  auto take = [&](size_t b) -> void* {
    void* p = w + off;
    off = (off + b + 255) & ~(size_t)255;
    return p;
  };
  float* rowsum = (float*)take(2 * 3 * K_N * 4);
  float* csum = (float*)take(2 * D_N * 4);
  float* csumsq = (float*)take(2 * D_N * 4);
  float* probsum = (float*)take(K_N * 4);
  int* counts = (int*)take(K_N * 4);
  float* scal = (float*)take(64);
  size_t zero_bytes = off;
  u16* zn1 = (u16*)take((size_t)B_N * D_N * 2);
  u16* zn2 = (u16*)take((size_t)B_N * D_N * 2);
  u16* Wb = (u16*)take((size_t)K_N * D_N * 2);
  u16* L1 = (u16*)take((size_t)B_N * K_N * 2);
  u16* L2 = (u16*)take((size_t)B_N * K_N * 2);
  float* Gpart = (float*)take((size_t)2 * 16 * 36 * 4096 * 4);
  // raw-bf16 z aliases the (not yet live) L1 buffer; gram/colstats finish before k_logits
  u16* zb1 = L1;
  u16* zb2 = L1 + (size_t)B_N * D_N;

  hipMemsetAsync(d_ws, 0, zero_bytes, stream);

  k_rownorm<<<8192, 256, 0, stream>>>(z1, z2, zn1, zn2, zb1, zb2);
  k_convW<<<512, 256, 0, stream>>>(W, Wb);
  k_colstats<<<dim3(1, 128, 2), dim3(64, 8), 0, stream>>>(zb1, zb2, csum, csumsq);
  k_vloss<<<4, 256, 0, stream>>>(csum, csumsq, scal);
  k_gram<<<dim3(36, 1, 32), 256, 0, stream>>>(zb1, zb2, Gpart);
  k_covreduce<<<dim3(36 * 16, 2), 256, 0, stream>>>(Gpart, csum, scal);
  k_logits<<<dim3(128, 16, 2), 256, 0, stream>>>(zn1, zn2, Wb, L1, L2, rowsum);
  k_sink<<<dim3(512, 2), 256, 0, stream>>>(L1, L2, rowsum, 0);
  k_sink<<<dim3(512, 2), 256, 0, stream>>>(L1, L2, rowsum, 1);
  k_final<<<256, 256, 0, stream>>>(L1, L2, rowsum, probsum, counts, scal);
  k_combine<<<1, 256, 0, stream>>>(scal, probsum, counts, (float*)d_out);
}